// Round 4
// baseline (419.345 us; speedup 1.0000x reference)
//
#include <hip/hip_runtime.h>

typedef float v4f __attribute__((ext_vector_type(4)));

#define BATCH 16384
#define NS    5
#define NCTX  10
#define XSTR  (NCTX + 2)
#define D4    75          // 300 floats = 75 float4; rows are 1200B -> 16B aligned
#define HI    11          // chunks 64..74
#define NBLK  1024        // 1024 blocks x 4 waves x 4 rows/wave = 16384 rows

// 4 rows per wave, interleaved. Lane l owns float4 chunk l of each row's
// 300-dim vectors (chunks 0..63). The leftover "hi" chunks (64..74) of all 4
// rows are packed into ONE 44-lane gather: lane l handles row (l/11), chunk
// 64+(l-11*(l/11)). Because the output is summed over the batch, hi partial
// products from different rows can share the same wave-level accumulator --
// no per-row separation needed. Ws (300 MB, ~single-use) is loaded
// non-temporally so it doesn't displace the hot 60 MB Wg table in cache.
__global__ __launch_bounds__(256, 4) void sense_partials(
    const int*   __restrict__ x,
    const float* __restrict__ Wg,
    const float* __restrict__ Ws,
    float*       __restrict__ partial /* [NS][NBLK] */) {
  const int lane = threadIdx.x & 63;
  const int wid  = threadIdx.x >> 6;          // 4 waves per block
  const int grp  = blockIdx.x * 4 + wid;      // 0..4095
  const int b0   = grp * 4;                   // rows b0 .. b0+3

  const v4f* Wg4 = (const v4f*)Wg;
  const v4f* Ws4 = (const v4f*)Ws;

  // all 4 rows' x entries in one 48-lane load
  int v = (lane < 4 * XSTR) ? x[(size_t)b0 * XSTR + lane] : 0;

  // hi-lane mapping: lane -> (row hr, chunk 64+hc), valid for lane < 44
  const int hr = lane / HI;                   // 0..3 for lane<44
  const int hc = lane - hr * HI;              // 0..10
  const bool hiOn = (lane < 4 * HI);

  // per-row word0 / context indices via shuffles from v
  int w0[4];
#pragma unroll
  for (int r = 0; r < 4; ++r) w0[r] = __shfl(v, r * XSTR);
  const int wH = __shfl(v, hr * XSTR);        // my hi-row's word0 (lane<44)

  v4f s0[4] = {0.f, 0.f, 0.f, 0.f};           // lo accumulators, per row
  v4f sH    = 0.f;                            // shared hi accumulator (44 lanes)

#pragma unroll
  for (int j = 0; j < NCTX; ++j) {
    int c0 = __shfl(v, 0 * XSTR + 2 + j);
    int c1 = __shfl(v, 1 * XSTR + 2 + j);
    int c2 = __shfl(v, 2 * XSTR + 2 + j);
    int c3 = __shfl(v, 3 * XSTR + 2 + j);
    int cH = __shfl(v, hr * XSTR + 2 + j);    // divergent-index shfl (bpermute)
    s0[0] += Wg4[(size_t)c0 * D4 + lane];
    s0[1] += Wg4[(size_t)c1 * D4 + lane];
    s0[2] += Wg4[(size_t)c2 * D4 + lane];
    s0[3] += Wg4[(size_t)c3 * D4 + lane];
    if (hiOn) sH += Wg4[(size_t)cH * D4 + 64 + hc];
  }

  const v4f* wb0 = Ws4 + (size_t)w0[0] * (NS * D4);
  const v4f* wb1 = Ws4 + (size_t)w0[1] * (NS * D4);
  const v4f* wb2 = Ws4 + (size_t)w0[2] * (NS * D4);
  const v4f* wb3 = Ws4 + (size_t)w0[3] * (NS * D4);
  const v4f* wbH = Ws4 + (size_t)wH    * (NS * D4);

  float acc[NS];
#pragma unroll
  for (int s = 0; s < NS; ++s) {
    v4f p = __builtin_nontemporal_load(&wb0[s * D4 + lane]) * s0[0]
          + __builtin_nontemporal_load(&wb1[s * D4 + lane]) * s0[1]
          + __builtin_nontemporal_load(&wb2[s * D4 + lane]) * s0[2]
          + __builtin_nontemporal_load(&wb3[s * D4 + lane]) * s0[3];
    if (hiOn)
      p += __builtin_nontemporal_load(&wbH[s * D4 + 64 + hc]) * sH;
    acc[s] = p.x + p.y + p.z + p.w;
  }

  // wave reduction (64 lanes) -- rows already folded together
#pragma unroll
  for (int s = 0; s < NS; ++s) {
    float t = acc[s];
#pragma unroll
    for (int off = 32; off; off >>= 1) t += __shfl_down(t, off);
    acc[s] = t;
  }

  __shared__ float red[4][NS];
  if (lane == 0) {
#pragma unroll
    for (int s = 0; s < NS; ++s) red[wid][s] = acc[s];
  }
  __syncthreads();
  if (threadIdx.x < NS) {
    float t = red[0][threadIdx.x] + red[1][threadIdx.x] +
              red[2][threadIdx.x] + red[3][threadIdx.x];
    partial[threadIdx.x * NBLK + blockIdx.x] = t;   // s-major for easy reduce
  }
}

// Kernel 2: 5 waves, wave s reduces partial[s][*], writes sigmoid.
__global__ __launch_bounds__(320) void sense_reduce(
    const float* __restrict__ partial, float* __restrict__ out) {
  const int lane = threadIdx.x & 63;
  const int s    = threadIdx.x >> 6;   // 0..4
  float sum = 0.f;
  for (int g = lane; g < NBLK; g += 64) sum += partial[s * NBLK + g];
#pragma unroll
  for (int off = 32; off; off >>= 1) sum += __shfl_down(sum, off);
  if (lane == 0) out[s] = 1.0f / (1.0f + __expf(-sum));
}

extern "C" void kernel_launch(void* const* d_in, const int* in_sizes, int n_in,
                              void* d_out, int out_size, void* d_ws, size_t ws_size,
                              hipStream_t stream) {
  const int*   x  = (const int*)d_in[0];
  const float* Wg = (const float*)d_in[1];
  const float* Ws = (const float*)d_in[2];
  float* partial  = (float*)d_ws;          // NS*NBLK*4 = 20 KB
  float* out      = (float*)d_out;

  sense_partials<<<NBLK, 256, 0, stream>>>(x, Wg, Ws, partial);
  sense_reduce<<<1, 320, 0, stream>>>(partial, out);
}